// Round 2
// baseline (381.292 us; speedup 1.0000x reference)
//
#include <hip/hip_runtime.h>

#define BB   8
#define CC   64
#define HWN  19200
#define NPTS 12800
#define NSUB 3200
#define KNN  16
#define OUTN (HWN + NSUB)   // 22400

#define GRID_BLOCKS 512

typedef __attribute__((ext_vector_type(8))) short short8;
typedef __attribute__((ext_vector_type(4))) float floatx4;

__device__ __forceinline__ unsigned short f2bf(float f) {
    union { float f; unsigned int i; } v; v.f = f;
    unsigned int r = v.i + 0x7fffu + ((v.i >> 16) & 1u);
    return (unsigned short)(r >> 16);
}
__device__ __forceinline__ float bf2f(unsigned short u) {
    union { unsigned int i; float f; } v; v.i = ((unsigned int)u) << 16; return v.f;
}

struct P {
    const float* pfeat; const float* rgb;
    const float* w0; const float* w1; const float* w2; const float* w3;
    const float* s_pp; const float* b_pp;
    const float* s_rp; const float* b_rp;
    const float* s_pf; const float* b_pf;
    const float* s_rf; const float* b_rf;
    const int* pool_idx; const int* p2r_idx; const int* r2p_idx;
    ushort* wB; ushort* pfT; ushort* rgbT;
    ushort* pe0T; ushort* p2rT; ushort* r2pT;
    unsigned* bar;      // [0]=cnt, [16]=gen (separate cachelines)
    float* out;
};

// Software grid barrier: generation-based, device-scope atomics + threadfence
// (agent-scope fence emits L2 writeback/inv -> cross-XCD visibility).
// Safe because all GRID_BLOCKS blocks are co-resident: 2 blocks/CU, VGPR<=256
// enforced by __launch_bounds__(256,2), LDS 2x16.6KB << 160KB.
__device__ __forceinline__ void gbar(unsigned* cnt, unsigned* gen) {
    __syncthreads();                      // drains all block stores (vmcnt 0)
    if (threadIdx.x == 0) {
        __threadfence();                  // publish this XCD's L2
        unsigned g = __hip_atomic_load(gen, __ATOMIC_ACQUIRE, __HIP_MEMORY_SCOPE_AGENT);
        unsigned old = __hip_atomic_fetch_add(cnt, 1u, __ATOMIC_ACQ_REL, __HIP_MEMORY_SCOPE_AGENT);
        if (old == GRID_BLOCKS - 1) {
            __hip_atomic_store(cnt, 0u, __ATOMIC_RELAXED, __HIP_MEMORY_SCOPE_AGENT);
            __threadfence();
            __hip_atomic_fetch_add(gen, 1u, __ATOMIC_RELEASE, __HIP_MEMORY_SCOPE_AGENT);
        } else {
            while (__hip_atomic_load(gen, __ATOMIC_ACQUIRE, __HIP_MEMORY_SCOPE_AGENT) == g)
                __builtin_amdgcn_s_sleep(8);
        }
        __threadfence();                  // invalidate stale lines before reads
    }
    __syncthreads();
}

// ---------------------------------------------------------------------------
// Fused kernel: phase1 (transpose+weights, 2096 vblocks), gbar,
// phase2 (gather+maxpool+preconv, 800 vblocks), gbar, phase3 (fuse GEMMs,
// 704 vblocks). Phase bodies identical to the verified R8 3-kernel version;
// grid-stride of 512 preserves b==XCD L2 alignment (512 % 8 == 0).
// ---------------------------------------------------------------------------
__global__ __launch_bounds__(256, 2) void k_all(P p) {
    __shared__ alignas(16) ushort sm[2][64 * 65];   // 16640 B; phase2 reuses as [64*72]
    int tid = threadIdx.x;

    // ---------------- PHASE 1: transpose f32 [B][C][N] -> bf16 [B][N][C] ----
    for (int w = blockIdx.x; w < 2096; w += GRID_BLOCKS) {
        if (w >= 2000) {
            int i = (w - 2000) * 256 + tid;
            float v;
            if (i < 4096)       v = p.w0[i];
            else if (i < 8192)  v = p.w1[i - 4096];
            else if (i < 16384) v = p.w2[i - 8192];
            else                v = p.w3[i - 16384];
            p.wB[i] = f2bf(v);
        } else {
            bool isR = (w >= 800);
            int v0 = isR ? w - 800 : w;
            int b = v0 & 7, xx = v0 >> 3;
            const float* src = (isR ? p.rgb : p.pfeat);
            ushort* outp     = (isR ? p.rgbT : p.pfT);
            int N  = isR ? HWN : NPTS;
            int n0 = xx * 128;
            src += (size_t)b * CC * N + n0;

            int l = tid & 15, ch = tid >> 4;
            float4 v[2][4];
            #pragma unroll
            for (int s = 0; s < 2; ++s)
                #pragma unroll
                for (int it = 0; it < 4; ++it)
                    v[s][it] = *(const float4*)(src + (size_t)(ch + 16 * it) * N + s * 64 + 4 * l);
            #pragma unroll
            for (int s = 0; s < 2; ++s)
                #pragma unroll
                for (int it = 0; it < 4; ++it) {
                    int c = ch + 16 * it;
                    sm[s][c * 65 + 4 * l + 0] = f2bf(v[s][it].x);
                    sm[s][c * 65 + 4 * l + 1] = f2bf(v[s][it].y);
                    sm[s][c * 65 + 4 * l + 2] = f2bf(v[s][it].z);
                    sm[s][c * 65 + 4 * l + 3] = f2bf(v[s][it].w);
                }
            __syncthreads();
            ushort* dst = outp + ((size_t)b * N + n0) * CC;
            int c8 = (tid & 7) * 8;
            #pragma unroll
            for (int pass = 0; pass < 4; ++pass) {
                int n_loc = (tid >> 3) + 32 * pass;
                int s = n_loc >> 6, n = n_loc & 63;
                short8 r;
                #pragma unroll
                for (int u = 0; u < 8; ++u)
                    r[u] = (short)sm[s][(c8 + u) * 65 + n];
                *(short8*)(dst + (size_t)n_loc * CC + c8) = r;
            }
        }
        __syncthreads();   // protect sm reuse across grid-stride iterations
    }
    gbar(p.bar, p.bar + 16);

    // ---------------- PHASE 2: gather + maxpool + pre-conv GEMM -------------
    ushort* sg = &sm[0][0];   // reused as [64*72]
    for (int w = blockIdx.x; w < 800; w += GRID_BLOCKS) {
        bool pt = (w < 400);
        int v0 = pt ? w : w - 400;
        int b = v0 & 7, xx = v0 >> 3;
        int m0 = xx * 64;
        const ushort* xT  = pt ? p.pfT : p.rgbT;
        const int*    idx = pt ? p.pool_idx : p.r2p_idx;
        int Nin           = pt ? NPTS : HWN;
        const ushort* W   = pt ? p.wB : p.wB + 4096;   // [64][64]
        const float*  sv  = pt ? p.s_pp : p.s_rp;
        const float*  bv  = pt ? p.b_pp : p.b_rp;
        ushort*       dst = pt ? p.p2rT : p.r2pT;

        int c8   = (tid & 7) * 8;
        int mloc = tid >> 3;          // 0..31: 32 points per pass
        const ushort* xb = xT + (size_t)b * Nin * CC + c8;
        #pragma unroll
        for (int pass = 0; pass < 2; ++pass) {
            int ml = mloc + pass * 32;
            int m  = m0 + ml;
            const int4* ip4 = (const int4*)(idx + ((size_t)b * NSUB + m) * KNN);
            int4 q0 = ip4[0], q1 = ip4[1], q2 = ip4[2], q3 = ip4[3];
            int js[16] = { q0.x, q0.y, q0.z, q0.w, q1.x, q1.y, q1.z, q1.w,
                           q2.x, q2.y, q2.z, q2.w, q3.x, q3.y, q3.z, q3.w };
            float a[8];
            #pragma unroll
            for (int u = 0; u < 8; ++u) a[u] = -1e30f;
            #pragma unroll
            for (int k = 0; k < KNN; ++k) {
                short8 val = *(const short8*)(xb + (size_t)js[k] * CC);
                #pragma unroll
                for (int u = 0; u < 8; ++u)
                    a[u] = fmaxf(a[u], bf2f((unsigned short)val[u]));
            }
            short8 r;
            #pragma unroll
            for (int u = 0; u < 8; ++u) r[u] = (short)f2bf(a[u]);
            *(short8*)(&sg[ml * 72 + c8]) = r;
            if (pt)
                *(short8*)(p.pe0T + ((size_t)b * NSUB + m) * CC + c8) = r;
        }
        __syncthreads();
        int wave = tid >> 6, lane = tid & 63;
        int l15 = lane & 15, quad = lane >> 4;
        int nloc0 = wave * 16;
        floatx4 acc[4] = {{0.f,0.f,0.f,0.f},{0.f,0.f,0.f,0.f},{0.f,0.f,0.f,0.f},{0.f,0.f,0.f,0.f}};
        #pragma unroll
        for (int kk = 0; kk < 2; ++kk) {
            short8 a = *(const short8*)(&sg[(nloc0 + l15) * 72 + kk * 32 + quad * 8]);
            #pragma unroll
            for (int t = 0; t < 4; ++t) {
                short8 wf = *(const short8*)(W + (size_t)(t * 16 + l15) * CC + kk * 32 + quad * 8);
                acc[t] = __builtin_amdgcn_mfma_f32_16x16x32_bf16(a, wf, acc[t], 0, 0, 0);
            }
        }
        #pragma unroll
        for (int t = 0; t < 4; ++t) {
            int o = t * 16 + l15;
            float ss = sv[o], bb2 = bv[o];
            #pragma unroll
            for (int r = 0; r < 4; ++r) {
                int n = m0 + nloc0 + quad * 4 + r;
                float y = fmaxf(acc[t][r] * ss + bb2, 0.f);
                dst[((size_t)b * NSUB + n) * CC + o] = f2bf(y);
            }
        }
        __syncthreads();   // protect sg reuse across grid-stride iterations
    }
    gbar(p.bar, p.bar + 16);

    // ---------------- PHASE 3: both fuse GEMMs -> d_out ---------------------
    for (int w = blockIdx.x; w < 704; w += GRID_BLOCKS) {
        bool rp = (w < 600);
        int v0 = rp ? w : w - 600;
        int b = v0 & 7, x0 = v0 >> 3;     // rgb 0..74 / pt 0..12
        const ushort* x1T = rp ? p.rgbT : p.pe0T;
        const ushort* x2T = rp ? p.p2rT : p.r2pT;
        int N             = rp ? HWN : NSUB;
        int pos0          = rp ? 0 : HWN;
        const ushort* W   = rp ? p.wB + 8192 : p.wB + 16384;   // [64][128]
        const float*  sv  = rp ? p.s_pf : p.s_rf;
        const float*  bv  = rp ? p.b_pf : p.b_rf;

        int wave = tid >> 6, lane = tid & 63;
        int l15 = lane & 15, quad = lane >> 4;
        int n_base = x0 * 256 + wave * 64;
        int ncol   = n_base + l15 * 4;
        bool act   = rp || (ncol < NSUB);
        int nc     = act ? ncol : 0;

        // preload all B-fragments: xf[kk][g], 16 independent 16B loads
        short8 xf[4][4];
        {
            const ushort* r1[4];
            const ushort* r2[4];
            if (rp) {
                int4 i4 = *(const int4*)(p.p2r_idx + (size_t)b * N + nc);
                int n2s[4] = { i4.x, i4.y, i4.z, i4.w };
                #pragma unroll
                for (int g = 0; g < 4; ++g) {
                    r1[g] = x1T + ((size_t)b * N + nc + g) * CC + quad * 8;
                    r2[g] = x2T + ((size_t)b * NSUB + n2s[g]) * CC + quad * 8;
                }
            } else {
                #pragma unroll
                for (int g = 0; g < 4; ++g) {
                    r1[g] = x1T + ((size_t)b * N + nc + g) * CC + quad * 8;
                    r2[g] = x2T + ((size_t)b * NSUB + nc + g) * CC + quad * 8;
                }
            }
            #pragma unroll
            for (int g = 0; g < 4; ++g) {
                xf[0][g] = *(const short8*)(r1[g]);
                xf[1][g] = *(const short8*)(r1[g] + 32);
                xf[2][g] = *(const short8*)(r2[g]);
                xf[3][g] = *(const short8*)(r2[g] + 32);
            }
        }

        float* outb = p.out + (size_t)b * CC * OUTN + pos0 + nc;
        #pragma unroll
        for (int t = 0; t < 4; ++t) {
            floatx4 acc[4] = {{0.f,0.f,0.f,0.f},{0.f,0.f,0.f,0.f},
                              {0.f,0.f,0.f,0.f},{0.f,0.f,0.f,0.f}};
            #pragma unroll
            for (int kk = 0; kk < 4; ++kk) {
                short8 wf = *(const short8*)(W + (size_t)(t * 16 + l15) * 128 + kk * 32 + quad * 8);
                #pragma unroll
                for (int g = 0; g < 4; ++g)
                    acc[g] = __builtin_amdgcn_mfma_f32_16x16x32_bf16(wf, xf[kk][g], acc[g], 0, 0, 0);
            }
            // store tile t immediately: overlaps next tile's MFMA
            #pragma unroll
            for (int r = 0; r < 4; ++r) {
                int o = t * 16 + quad * 4 + r;
                float ss = sv[o], bb2 = bv[o];
                floatx4 y;
                y[0] = fmaxf(acc[0][r] * ss + bb2, 0.f);
                y[1] = fmaxf(acc[1][r] * ss + bb2, 0.f);
                y[2] = fmaxf(acc[2][r] * ss + bb2, 0.f);
                y[3] = fmaxf(acc[3][r] * ss + bb2, 0.f);
                if (act)
                    __builtin_nontemporal_store(y, (floatx4*)(outb + (size_t)o * OUTN));
            }
        }
    }
}

extern "C" void kernel_launch(void* const* d_in, const int* in_sizes, int n_in,
                              void* d_out, int out_size, void* d_ws, size_t ws_size,
                              hipStream_t stream) {
    char* ws = (char*)d_ws;
    ushort* wB   = (ushort*)ws; ws += 24576 * 2;
    ushort* pfT  = (ushort*)ws; ws += (size_t)BB * NPTS * CC * 2;
    ushort* rgbT = (ushort*)ws; ws += (size_t)BB * HWN  * CC * 2;
    ushort* pe0T = (ushort*)ws; ws += (size_t)BB * NSUB * CC * 2;
    ushort* p2rT = (ushort*)ws; ws += (size_t)BB * NSUB * CC * 2;
    ushort* r2pT = (ushort*)ws; ws += (size_t)BB * NSUB * CC * 2;
    unsigned* bar = (unsigned*)ws; ws += 256;

    // re-arm the grid barrier every iteration (workspace is poisoned between runs)
    hipMemsetAsync(bar, 0, 256, stream);

    P p;
    p.pfeat = (const float*)d_in[1];
    p.rgb   = (const float*)d_in[0];
    p.w0    = (const float*)d_in[2];
    p.w1    = (const float*)d_in[8];
    p.w2    = (const float*)d_in[5];
    p.w3    = (const float*)d_in[11];
    p.s_pp  = (const float*)d_in[3];   p.b_pp = (const float*)d_in[4];
    p.s_rp  = (const float*)d_in[9];   p.b_rp = (const float*)d_in[10];
    p.s_pf  = (const float*)d_in[6];   p.b_pf = (const float*)d_in[7];
    p.s_rf  = (const float*)d_in[12];  p.b_rf = (const float*)d_in[13];
    p.pool_idx = (const int*)d_in[14];
    p.p2r_idx  = (const int*)d_in[15];
    p.r2p_idx  = (const int*)d_in[16];
    p.wB = wB; p.pfT = pfT; p.rgbT = rgbT;
    p.pe0T = pe0T; p.p2rT = p2rT; p.r2pT = r2pT;
    p.bar = bar;
    p.out = (float*)d_out;

    k_all<<<dim3(GRID_BLOCKS), 256, 0, stream>>>(p);
}

// Round 3
// 232.644 us; speedup vs baseline: 1.6389x; 1.6389x over previous
//
#include <hip/hip_runtime.h>

#define BB   8
#define CC   64
#define HWN  19200
#define NPTS 12800
#define NSUB 3200
#define KNN  16
#define OUTN (HWN + NSUB)   // 22400

#define GRID_BLOCKS 512
#define NGRP  8            // groups == batches == XCDs (bid & 7)
#define GBLK  64           // blocks per group

typedef __attribute__((ext_vector_type(8))) short short8;
typedef __attribute__((ext_vector_type(4))) float floatx4;

__device__ __forceinline__ unsigned short f2bf(float f) {
    union { float f; unsigned int i; } v; v.f = f;
    unsigned int r = v.i + 0x7fffu + ((v.i >> 16) & 1u);
    return (unsigned short)(r >> 16);
}
__device__ __forceinline__ float bf2f(unsigned short u) {
    union { unsigned int i; float f; } v; v.i = ((unsigned int)u) << 16; return v.f;
}

struct P {
    const float* pfeat; const float* rgb;
    const float* w0; const float* w1; const float* w2; const float* w3;
    const float* s_pp; const float* b_pp;
    const float* s_rp; const float* b_rp;
    const float* s_pf; const float* b_pf;
    const float* s_rf; const float* b_rf;
    const int* pool_idx; const int* p2r_idx; const int* r2p_idx;
    ushort* wB; ushort* pfT; ushort* rgbT;
    ushort* pe0T; ushort* p2rT; ushort* r2pT;
    unsigned* bar;
    float* out;
};

// Per-group (64-block) barrier, flag-array + generation broadcast.
// Layout in p.bar: gen[g] at bar[g*16]; flag[g][lj] at bar[128 + (g*64+lj)*16]
// (64B spacing -> no line sharing). Arrival = one plain device-scope store per
// block (parallel, unlike same-address RMW which serialized ~200ns x 512 in R2).
// Master (lj==0) polls 63 flags with 63 threads, then publishes gen[g].
// Co-residency: 512 blocks @ 2/CU guaranteed by __launch_bounds__(256,2).
__device__ __forceinline__ void gbar(unsigned* bar, int g, int lj, unsigned phase) {
    __syncthreads();
    unsigned* genp = bar + g * 16;
    unsigned* flg  = bar + 128 + (g * 64) * 16;
    int tid = threadIdx.x;
    if (lj == 0) {
        for (int j = 1 + tid; j < GBLK; j += 256)
            while (__hip_atomic_load(flg + j * 16, __ATOMIC_RELAXED, __HIP_MEMORY_SCOPE_AGENT) < phase)
                __builtin_amdgcn_s_sleep(2);
        __syncthreads();
        if (tid == 0) {
            __threadfence();   // flush own stores + invalidate stale lines (wbl2+inv)
            __hip_atomic_store(genp, phase, __ATOMIC_RELEASE, __HIP_MEMORY_SCOPE_AGENT);
        }
        __syncthreads();
    } else {
        if (tid == 0) {
            __threadfence();   // publish this block's phase stores
            __hip_atomic_store(flg + lj * 16, phase, __ATOMIC_RELAXED, __HIP_MEMORY_SCOPE_AGENT);
            while (__hip_atomic_load(genp, __ATOMIC_RELAXED, __HIP_MEMORY_SCOPE_AGENT) < phase)
                __builtin_amdgcn_s_sleep(8);
            __threadfence();   // invalidate stale lines before reading remote data
        }
        __syncthreads();
    }
}

// ---------------------------------------------------------------------------
// Fused kernel, per-batch groups: group g (= bid&7 = batch = XCD) runs
// phase1 (transpose 250 vb + weights 6 vb), gbar, phase2 (100 vb), gbar,
// phase3 (88 vb) for batch g only. Groups are fully independent (all gathers
// are intra-batch). Phase bodies identical to the verified R8 kernels.
// ---------------------------------------------------------------------------
__global__ __launch_bounds__(256, 2) void k_all(P p) {
    __shared__ alignas(16) ushort sm[2][64 * 65];   // 16640 B; phase2 reuses as [64*72]
    int tid = threadIdx.x;
    int bid = blockIdx.x;
    int g   = bid & 7;      // batch / group / XCD
    int lj  = bid >> 3;     // 0..63 local block id
    ushort* wBg = p.wB + (size_t)g * 24576;

    // ---- PHASE 1: transpose f32 [C][N] -> bf16 [N][C] for batch g + weights
    for (int vb = lj; vb < 256; vb += GBLK) {
        if (vb >= 250) {
            // weight slice (vb-250) in [0,6): 4096 elems, 16/thread, region-uniform
            int i0 = (vb - 250) * 4096 + tid * 16;
            const float* wsrc; int roff;
            if (i0 < 4096)       { wsrc = p.w0; roff = i0; }
            else if (i0 < 8192)  { wsrc = p.w1; roff = i0 - 4096; }
            else if (i0 < 16384) { wsrc = p.w2; roff = i0 - 8192; }
            else                 { wsrc = p.w3; roff = i0 - 16384; }
            #pragma unroll
            for (int q = 0; q < 16; q += 4) {
                float4 v = *(const float4*)(wsrc + roff + q);
                ushort4 r;
                r.x = f2bf(v.x); r.y = f2bf(v.y); r.z = f2bf(v.z); r.w = f2bf(v.w);
                *(ushort4*)(wBg + i0 + q) = r;
            }
        } else {
            bool isR = (vb >= 100);
            int xx = isR ? vb - 100 : vb;
            const float* src = (isR ? p.rgb : p.pfeat);
            ushort* outp     = (isR ? p.rgbT : p.pfT);
            int N  = isR ? HWN : NPTS;
            int n0 = xx * 128;
            src += (size_t)g * CC * N + n0;

            int l = tid & 15, ch = tid >> 4;
            float4 v[2][4];
            #pragma unroll
            for (int s = 0; s < 2; ++s)
                #pragma unroll
                for (int it = 0; it < 4; ++it)
                    v[s][it] = *(const float4*)(src + (size_t)(ch + 16 * it) * N + s * 64 + 4 * l);
            #pragma unroll
            for (int s = 0; s < 2; ++s)
                #pragma unroll
                for (int it = 0; it < 4; ++it) {
                    int c = ch + 16 * it;
                    sm[s][c * 65 + 4 * l + 0] = f2bf(v[s][it].x);
                    sm[s][c * 65 + 4 * l + 1] = f2bf(v[s][it].y);
                    sm[s][c * 65 + 4 * l + 2] = f2bf(v[s][it].z);
                    sm[s][c * 65 + 4 * l + 3] = f2bf(v[s][it].w);
                }
            __syncthreads();
            ushort* dst = outp + ((size_t)g * N + n0) * CC;
            int c8 = (tid & 7) * 8;
            #pragma unroll
            for (int pass = 0; pass < 4; ++pass) {
                int n_loc = (tid >> 3) + 32 * pass;
                int s = n_loc >> 6, n = n_loc & 63;
                short8 r;
                #pragma unroll
                for (int u = 0; u < 8; ++u)
                    r[u] = (short)sm[s][(c8 + u) * 65 + n];
                *(short8*)(dst + (size_t)n_loc * CC + c8) = r;
            }
        }
        __syncthreads();   // protect sm reuse across grid-stride iterations
    }
    gbar(p.bar, g, lj, 1u);

    // ---- PHASE 2: gather + maxpool + pre-conv GEMM (batch g), 100 vblocks --
    ushort* sg = &sm[0][0];   // reused as [64*72]
    for (int vb = lj; vb < 100; vb += GBLK) {
        bool pt = (vb < 50);
        int xx = pt ? vb : vb - 50;
        int m0 = xx * 64;
        const ushort* xT  = pt ? p.pfT : p.rgbT;
        const int*    idx = pt ? p.pool_idx : p.r2p_idx;
        int Nin           = pt ? NPTS : HWN;
        const ushort* W   = pt ? wBg : wBg + 4096;   // [64][64]
        const float*  sv  = pt ? p.s_pp : p.s_rp;
        const float*  bv  = pt ? p.b_pp : p.b_rp;
        ushort*       dst = pt ? p.p2rT : p.r2pT;

        int c8   = (tid & 7) * 8;
        int mloc = tid >> 3;          // 0..31: 32 points per pass
        const ushort* xb = xT + (size_t)g * Nin * CC + c8;
        #pragma unroll
        for (int pass = 0; pass < 2; ++pass) {
            int ml = mloc + pass * 32;
            int m  = m0 + ml;
            const int4* ip4 = (const int4*)(idx + ((size_t)g * NSUB + m) * KNN);
            int4 q0 = ip4[0], q1 = ip4[1], q2 = ip4[2], q3 = ip4[3];
            int js[16] = { q0.x, q0.y, q0.z, q0.w, q1.x, q1.y, q1.z, q1.w,
                           q2.x, q2.y, q2.z, q2.w, q3.x, q3.y, q3.z, q3.w };
            float a[8];
            #pragma unroll
            for (int u = 0; u < 8; ++u) a[u] = -1e30f;
            #pragma unroll
            for (int k = 0; k < KNN; ++k) {
                short8 val = *(const short8*)(xb + (size_t)js[k] * CC);
                #pragma unroll
                for (int u = 0; u < 8; ++u)
                    a[u] = fmaxf(a[u], bf2f((unsigned short)val[u]));
            }
            short8 r;
            #pragma unroll
            for (int u = 0; u < 8; ++u) r[u] = (short)f2bf(a[u]);
            *(short8*)(&sg[ml * 72 + c8]) = r;
            if (pt)
                *(short8*)(p.pe0T + ((size_t)g * NSUB + m) * CC + c8) = r;
        }
        __syncthreads();
        int wave = tid >> 6, lane = tid & 63;
        int l15 = lane & 15, quad = lane >> 4;
        int nloc0 = wave * 16;
        floatx4 acc[4] = {{0.f,0.f,0.f,0.f},{0.f,0.f,0.f,0.f},{0.f,0.f,0.f,0.f},{0.f,0.f,0.f,0.f}};
        #pragma unroll
        for (int kk = 0; kk < 2; ++kk) {
            short8 a = *(const short8*)(&sg[(nloc0 + l15) * 72 + kk * 32 + quad * 8]);
            #pragma unroll
            for (int t = 0; t < 4; ++t) {
                short8 wf = *(const short8*)(W + (size_t)(t * 16 + l15) * CC + kk * 32 + quad * 8);
                acc[t] = __builtin_amdgcn_mfma_f32_16x16x32_bf16(a, wf, acc[t], 0, 0, 0);
            }
        }
        #pragma unroll
        for (int t = 0; t < 4; ++t) {
            int o = t * 16 + l15;
            float ss = sv[o], bb2 = bv[o];
            #pragma unroll
            for (int r = 0; r < 4; ++r) {
                int n = m0 + nloc0 + quad * 4 + r;
                float y = fmaxf(acc[t][r] * ss + bb2, 0.f);
                dst[((size_t)g * NSUB + n) * CC + o] = f2bf(y);
            }
        }
        __syncthreads();   // protect sg reuse across grid-stride iterations
    }
    gbar(p.bar, g, lj, 2u);

    // ---- PHASE 3: both fuse GEMMs -> d_out (batch g), 88 vblocks -----------
    for (int vb = lj; vb < 88; vb += GBLK) {
        bool rp = (vb < 75);
        int x0 = rp ? vb : vb - 75;       // rgb 0..74 / pt 0..12
        const ushort* x1T = rp ? p.rgbT : p.pe0T;
        const ushort* x2T = rp ? p.p2rT : p.r2pT;
        int N             = rp ? HWN : NSUB;
        int pos0          = rp ? 0 : HWN;
        const ushort* W   = rp ? wBg + 8192 : wBg + 16384;   // [64][128]
        const float*  sv  = rp ? p.s_pf : p.s_rf;
        const float*  bv  = rp ? p.b_pf : p.b_rf;

        int wave = tid >> 6, lane = tid & 63;
        int l15 = lane & 15, quad = lane >> 4;
        int n_base = x0 * 256 + wave * 64;
        int ncol   = n_base + l15 * 4;
        bool act   = rp || (ncol < NSUB);
        int nc     = act ? ncol : 0;

        // preload all B-fragments: xf[kk][gg], 16 independent 16B loads
        short8 xf[4][4];
        {
            const ushort* r1[4];
            const ushort* r2[4];
            if (rp) {
                int4 i4 = *(const int4*)(p.p2r_idx + (size_t)g * N + nc);
                int n2s[4] = { i4.x, i4.y, i4.z, i4.w };
                #pragma unroll
                for (int gg = 0; gg < 4; ++gg) {
                    r1[gg] = x1T + ((size_t)g * N + nc + gg) * CC + quad * 8;
                    r2[gg] = x2T + ((size_t)g * NSUB + n2s[gg]) * CC + quad * 8;
                }
            } else {
                #pragma unroll
                for (int gg = 0; gg < 4; ++gg) {
                    r1[gg] = x1T + ((size_t)g * N + nc + gg) * CC + quad * 8;
                    r2[gg] = x2T + ((size_t)g * NSUB + nc + gg) * CC + quad * 8;
                }
            }
            #pragma unroll
            for (int gg = 0; gg < 4; ++gg) {
                xf[0][gg] = *(const short8*)(r1[gg]);
                xf[1][gg] = *(const short8*)(r1[gg] + 32);
                xf[2][gg] = *(const short8*)(r2[gg]);
                xf[3][gg] = *(const short8*)(r2[gg] + 32);
            }
        }

        float* outb = p.out + (size_t)g * CC * OUTN + pos0 + nc;
        #pragma unroll
        for (int t = 0; t < 4; ++t) {
            floatx4 acc[4] = {{0.f,0.f,0.f,0.f},{0.f,0.f,0.f,0.f},
                              {0.f,0.f,0.f,0.f},{0.f,0.f,0.f,0.f}};
            #pragma unroll
            for (int kk = 0; kk < 4; ++kk) {
                short8 wf = *(const short8*)(W + (size_t)(t * 16 + l15) * 128 + kk * 32 + quad * 8);
                #pragma unroll
                for (int gg = 0; gg < 4; ++gg)
                    acc[gg] = __builtin_amdgcn_mfma_f32_16x16x32_bf16(wf, xf[kk][gg], acc[gg], 0, 0, 0);
            }
            // store tile t immediately: overlaps next tile's MFMA
            #pragma unroll
            for (int r = 0; r < 4; ++r) {
                int o = t * 16 + quad * 4 + r;
                float ss = sv[o], bb2 = bv[o];
                floatx4 y;
                y[0] = fmaxf(acc[0][r] * ss + bb2, 0.f);
                y[1] = fmaxf(acc[1][r] * ss + bb2, 0.f);
                y[2] = fmaxf(acc[2][r] * ss + bb2, 0.f);
                y[3] = fmaxf(acc[3][r] * ss + bb2, 0.f);
                if (act)
                    __builtin_nontemporal_store(y, (floatx4*)(outb + (size_t)o * OUTN));
            }
        }
    }
}

extern "C" void kernel_launch(void* const* d_in, const int* in_sizes, int n_in,
                              void* d_out, int out_size, void* d_ws, size_t ws_size,
                              hipStream_t stream) {
    char* ws = (char*)d_ws;
    ushort* wB   = (ushort*)ws; ws += (size_t)NGRP * 24576 * 2;   // 8 group copies
    ushort* pfT  = (ushort*)ws; ws += (size_t)BB * NPTS * CC * 2;
    ushort* rgbT = (ushort*)ws; ws += (size_t)BB * HWN  * CC * 2;
    ushort* pe0T = (ushort*)ws; ws += (size_t)BB * NSUB * CC * 2;
    ushort* p2rT = (ushort*)ws; ws += (size_t)BB * NSUB * CC * 2;
    ushort* r2pT = (ushort*)ws; ws += (size_t)BB * NSUB * CC * 2;
    unsigned* bar = (unsigned*)ws; ws += 36864;

    // re-arm barriers every iteration (workspace is poisoned between runs):
    // gens 512B + 8*64 flags * 64B = 33280B
    hipMemsetAsync(bar, 0, 33280, stream);

    P p;
    p.pfeat = (const float*)d_in[1];
    p.rgb   = (const float*)d_in[0];
    p.w0    = (const float*)d_in[2];
    p.w1    = (const float*)d_in[8];
    p.w2    = (const float*)d_in[5];
    p.w3    = (const float*)d_in[11];
    p.s_pp  = (const float*)d_in[3];   p.b_pp = (const float*)d_in[4];
    p.s_rp  = (const float*)d_in[9];   p.b_rp = (const float*)d_in[10];
    p.s_pf  = (const float*)d_in[6];   p.b_pf = (const float*)d_in[7];
    p.s_rf  = (const float*)d_in[12];  p.b_rf = (const float*)d_in[13];
    p.pool_idx = (const int*)d_in[14];
    p.p2r_idx  = (const int*)d_in[15];
    p.r2p_idx  = (const int*)d_in[16];
    p.wB = wB; p.pfT = pfT; p.rgbT = rgbT;
    p.pe0T = pe0T; p.p2rT = p2rT; p.r2pT = r2pT;
    p.bar = bar;
    p.out = (float*)d_out;

    k_all<<<dim3(GRID_BLOCKS), 256, 0, stream>>>(p);
}